// Round 13
// baseline (256.619 us; speedup 1.0000x reference)
//
#include <hip/hip_runtime.h>

// Problem constants
#define D_    2048
#define OUT_  2048
#define E_    8
#define R_    16
#define KX    2176          // D_ + E_*R_  (K-extended GEMM depth)
#define M_    16384         // B*S tokens
#define SCALING_F 2.0f      // ALPHA / R = 32/16

typedef unsigned short ushort_t;
typedef unsigned short ushort8 __attribute__((ext_vector_type(8)));
typedef __bf16 bf16x8 __attribute__((ext_vector_type(8)));
typedef float f32x4 __attribute__((ext_vector_type(4)));

__device__ __forceinline__ ushort_t f2bf(float f) {
  unsigned u = __float_as_uint(f);
  u += 0x7FFFu + ((u >> 16) & 1u);   // round-to-nearest-even
  return (ushort_t)(u >> 16);
}

#define GLOAD16(gp, lp)                                                        \
  __builtin_amdgcn_global_load_lds(                                            \
      (const __attribute__((address_space(1))) void*)(gp),                     \
      (__attribute__((address_space(3))) void*)(lp), 16, 0, 0)

// -------- W_ext + A_ext prep (fused): wext[OUT_][KX], aext[128][D_] bf16 ----
__global__ __launch_bounds__(256) void wprep_all_kernel(
    const float* __restrict__ W, const float* __restrict__ Bw,
    const float* __restrict__ A,
    ushort_t* __restrict__ wext, ushort_t* __restrict__ aext)
{
  const int bid = blockIdx.x;
  const int t = threadIdx.x;
  if (bid < OUT_) {
    const int o = bid;
    const float* wr = W + (size_t)o * D_ + t * 8;
    float4 v0 = *(const float4*)wr;
    float4 v1 = *(const float4*)(wr + 4);
    ushort8 wb;
    wb[0] = f2bf(v0.x); wb[1] = f2bf(v0.y); wb[2] = f2bf(v0.z); wb[3] = f2bf(v0.w);
    wb[4] = f2bf(v1.x); wb[5] = f2bf(v1.y); wb[6] = f2bf(v1.z); wb[7] = f2bf(v1.w);
    *(ushort8*)(wext + (size_t)o * KX + t * 8) = wb;
    if (t < E_ * R_) {
      const int e = t >> 4, r = t & 15;
      wext[(size_t)o * KX + D_ + t] = f2bf(Bw[((size_t)e * OUT_ + o) * R_ + r]);
    }
  } else {
    const size_t i = ((size_t)(bid - OUT_) * 256 + t) * 8;
    float4 v0 = *(const float4*)(A + i);
    float4 v1 = *(const float4*)(A + i + 4);
    ushort8 b;
    b[0] = f2bf(v0.x); b[1] = f2bf(v0.y); b[2] = f2bf(v0.z); b[3] = f2bf(v0.w);
    b[4] = f2bf(v1.x); b[5] = f2bf(v1.y); b[6] = f2bf(v1.z); b[7] = f2bf(v1.w);
    *(ushort8*)(aext + i) = b;
  }
}

// ---- per-token-wave prep: router + argmax + bf16 convert + h, NO LDS/sync --
// One wave per token; 4096 blocks x 4 waves. Lane owns elems lane*8+j*512
// (j=0..3). Zero barriers, zero LDS, wave-uniform expert branch. h computed
// fp32 x * (bf16 A -> f32) — more precise than the MFMA path it replaces.
__global__ __launch_bounds__(256) void tokwave_kernel(
    const float* __restrict__ x,       // [M_][D_] fp32
    const float* __restrict__ rW,      // [E_][D_] fp32
    const ushort_t* __restrict__ Ae,   // [128][D_] bf16
    ushort_t* __restrict__ xext)       // writes all KX cols of its row
{
  const int t = threadIdx.x, lane = t & 63, w = t >> 6;
  const size_t m = (size_t)blockIdx.x * 4 + w;   // token
  const float* xr = x + m * D_;
  ushort_t* xo = xext + m * KX;

  float xv[32];
  float la[E_];
  #pragma unroll
  for (int e = 0; e < E_; ++e) la[e] = 0.f;

  // load x slice, convert+store bf16 core, accumulate router partials
  #pragma unroll
  for (int j = 0; j < 4; ++j) {
    const int c = lane * 8 + j * 512;
    float4 a = *(const float4*)(xr + c);
    float4 b = *(const float4*)(xr + c + 4);
    xv[j * 8 + 0] = a.x; xv[j * 8 + 1] = a.y; xv[j * 8 + 2] = a.z; xv[j * 8 + 3] = a.w;
    xv[j * 8 + 4] = b.x; xv[j * 8 + 5] = b.y; xv[j * 8 + 6] = b.z; xv[j * 8 + 7] = b.w;
    ushort8 u;
    u[0] = f2bf(a.x); u[1] = f2bf(a.y); u[2] = f2bf(a.z); u[3] = f2bf(a.w);
    u[4] = f2bf(b.x); u[5] = f2bf(b.y); u[6] = f2bf(b.z); u[7] = f2bf(b.w);
    *(ushort8*)(xo + c) = u;
    #pragma unroll
    for (int e = 0; e < E_; ++e) {
      const float* wp = rW + (size_t)e * D_ + c;
      float4 w0 = *(const float4*)wp;
      float4 w1 = *(const float4*)(wp + 4);
      la[e] += a.x * w0.x + a.y * w0.y + a.z * w0.z + a.w * w0.w
             + b.x * w1.x + b.y * w1.y + b.z * w1.z + b.w * w1.w;
    }
  }

  // fp64 xor-tree (all lanes end with full sums) + first-max argmax
  double s[E_];
  #pragma unroll
  for (int e = 0; e < E_; ++e) s[e] = (double)la[e];
  #pragma unroll
  for (int off = 1; off <= 32; off <<= 1)
    #pragma unroll
    for (int e = 0; e < E_; ++e) s[e] += __shfl_xor(s[e], off, 64);
  int esel = 0; double best = s[0];
  #pragma unroll
  for (int e = 1; e < E_; ++e)
    if (s[e] > best) { best = s[e]; esel = e; }   // first-max tie-break

  // h[r] = x . A[esel][r]  (A base wave-uniform; bf16 loads, fp32 math)
  const ushort_t* Ar = Ae + (size_t)esel * R_ * D_;
  float h[R_];
  #pragma unroll
  for (int r = 0; r < R_; ++r) {
    float p = 0.f;
    #pragma unroll
    for (int j = 0; j < 4; ++j) {
      bf16x8 av = *(const bf16x8*)(Ar + (size_t)r * D_ + lane * 8 + j * 512);
      #pragma unroll
      for (int u = 0; u < 8; ++u) p += xv[j * 8 + u] * (float)av[u];
    }
    h[r] = p;
  }
  #pragma unroll
  for (int off = 1; off <= 32; off <<= 1)
    #pragma unroll
    for (int r = 0; r < R_; ++r) h[r] += __shfl_xor(h[r], off, 64);

  // ext cols: lanes 0..31 write 4 cols each; unrolled cndmask select (no
  // runtime-indexed array -> no scratch)
  if (lane < 32) {
    ushort4 v;
    #pragma unroll
    for (int k = 0; k < 4; ++k) {
      const int col = lane * 4 + k;
      const int rr = col & 15;
      float hv = h[0];
      #pragma unroll
      for (int r = 1; r < R_; ++r) hv = (rr == r) ? h[r] : hv;
      ushort_t val = ((col >> 4) == esel) ? f2bf(hv * SCALING_F) : (ushort_t)0;
      ((ushort_t*)&v)[k] = val;
    }
    *(ushort4*)(xo + D_ + lane * 4) = v;
  }
}

// ---------------- GEMM: 256x256, symmetric 8-phase / 2-K-tile schedule ------
// (byte-identical to rounds 10/12 — isolation; measured 144.6-145.9 us)
#define NKT (KX / 64)        // 34 K-tiles
#define NITER (NKT / 2)      // 17 iterations
#define NSTG (NKT * 4)       // 136 half-tile stages

__global__ __launch_bounds__(512, 2) void gemm_kernel(
    const ushort_t* __restrict__ Ag,   // [M_][KX] bf16
    const ushort_t* __restrict__ Bg,   // [OUT_][KX] bf16
    const float* __restrict__ bias,
    float* __restrict__ C)
{
  __shared__ __attribute__((aligned(16))) char lds[131072];

  const int t = threadIdx.x;
  const int lane = t & 63, w = t >> 6;
  const int wm = w >> 2, wn = w & 3;          // 2x4 wave grid; wave tile 128x64
  const int lr = lane & 15, lg = lane >> 4;
  const int koff = (lr & 7) << 4;             // read-side swizzle XOR (bytes)

  // XCD-bijective blockIdx swizzle (512 % 8 == 0)
  const int swz = (blockIdx.x & 7) * 64 + (blockIdx.x >> 3);
  const int bm = swz >> 3, bn = swz & 7;

  const int sg_row = t >> 3;
  const int sg_slotx = (t & 7) ^ ((t >> 3) & 7);   // pre-swizzled source slot
  const size_t aRow0 = (size_t)bm * 256;
  const size_t bRow0 = (size_t)bn * 256;

  // stage half-tile s: tile TT=s>>2, j=s&3 (0,1 = A halves; 2,3 = B halves)
  auto stage = [&](int s) {
    if (s >= NSTG) return;
    const int TT = s >> 2, j = s & 3;
    const int isB = j >> 1, half = j & 1;
    const ushort_t* src = isB ? Bg : Ag;
    const size_t gr0 = (isB ? bRow0 : aRow0) + half * 128;
    char* dst = lds + (TT & 1) * 65536 + isB * 32768 + half * 16384;
    #pragma unroll
    for (int g = 0; g < 2; ++g) {
      const int r = g * 64 + sg_row;
      GLOAD16(src + (gr0 + r) * KX + TT * 64 + sg_slotx * 8,
              dst + g * 8192 + t * 16);
    }
  };

  f32x4 acc[8][4] = {};
  bf16x8 bq[4][2];

  // prologue: tile0 {A0,A1,B0,B1} + tile1 {B0,B1}; wait tile0 landed,
  // leaving tile1's B (4 loads) in flight. (tile1's A staged at iter0 p0/p1.)
  stage(0); stage(1); stage(2); stage(3);
  stage(6); stage(7);
  asm volatile("s_waitcnt vmcnt(4)" ::: "memory");
  __builtin_amdgcn_s_barrier();

  for (int ii = 0; ii < NITER; ++ii) {
    #pragma unroll
    for (int p = 0; p < 8; ++p) {
      const int q = p & 3;
      char* Ab = lds + ((2 * ii + (p >> 2)) & 1) * 65536;
      char* Bb = Ab + 32768;
      // --- ds-load register subtile ---
      bf16x8 aq[2][2];
      if (q == 0) {
        #pragma unroll
        for (int nj = 0; nj < 4; ++nj) {
          const int R = wn * 64 + nj * 16 + lr;
          #pragma unroll
          for (int kk = 0; kk < 2; ++kk)
            bq[nj][kk] = *(const bf16x8*)(Bb + R * 128 + ((kk * 64 + lg * 16) ^ koff));
        }
      }
      #pragma unroll
      for (int i = 0; i < 2; ++i) {
        const int R = wm * 128 + (q * 2 + i) * 16 + lr;
        #pragma unroll
        for (int kk = 0; kk < 2; ++kk)
          aq[i][kk] = *(const bf16x8*)(Ab + R * 128 + ((kk * 64 + lg * 16) ^ koff));
      }
      // --- one half-tile stage per phase ---
      switch (p) {
        case 0: stage(4 * (2 * ii + 1) + 0); break;
        case 1: stage(4 * (2 * ii + 1) + 1); break;
        case 2: stage(4 * (2 * ii + 2) + 2); break;
        case 3: stage(4 * (2 * ii + 2) + 3); break;
        case 4: stage(4 * (2 * ii + 2) + 0); break;
        case 5: stage(4 * (2 * ii + 2) + 1); break;
        case 6: stage(4 * (2 * ii + 3) + 2); break;
        case 7: stage(4 * (2 * ii + 3) + 3); break;
      }
      if (q == 0) asm volatile("s_waitcnt lgkmcnt(8)" ::: "memory");
      __builtin_amdgcn_s_barrier();
      asm volatile("s_waitcnt lgkmcnt(0)" ::: "memory");
      // --- MFMA cluster: one C-quadrant (2 m-frags x 4 n-frags) x K=64 ---
      __builtin_amdgcn_s_setprio(1);
      #pragma unroll
      for (int i = 0; i < 2; ++i)
        #pragma unroll
        for (int nj = 0; nj < 4; ++nj)
          #pragma unroll
          for (int kk = 0; kk < 2; ++kk)
            acc[q * 2 + i][nj] = __builtin_amdgcn_mfma_f32_16x16x32_bf16(
                aq[i][kk], bq[nj][kk], acc[q * 2 + i][nj], 0, 0, 0);
      __builtin_amdgcn_s_setprio(0);
      if (p == 3 || p == 7) {
        if (ii == NITER - 1) asm volatile("s_waitcnt vmcnt(0)" ::: "memory");
        else                 asm volatile("s_waitcnt vmcnt(4)" ::: "memory");
      }
      __builtin_amdgcn_s_barrier();
    }
  }

  // epilogue: C = acc + bias ; C/D layout col=lane&15, row=(lane>>4)*4+reg
  #pragma unroll
  for (int nj = 0; nj < 4; ++nj) {
    const int col = bn * 256 + wn * 64 + nj * 16 + lr;
    const float bv = bias[col];
    #pragma unroll
    for (int mi = 0; mi < 8; ++mi) {
      const int row0 = bm * 256 + wm * 128 + mi * 16 + lg * 4;
      #pragma unroll
      for (int rr = 0; rr < 4; ++rr)
        C[(size_t)(row0 + rr) * OUT_ + col] = acc[mi][nj][rr] + bv;
    }
  }
}

extern "C" void kernel_launch(void* const* d_in, const int* in_sizes, int n_in,
                              void* d_out, int out_size, void* d_ws, size_t ws_size,
                              hipStream_t stream) {
  const float* x  = (const float*)d_in[0];   // [4,4096,2048]
  const float* Wb = (const float*)d_in[1];   // [2048,2048]
  const float* bb = (const float*)d_in[2];   // [2048]
  const float* rW = (const float*)d_in[3];   // [8,2048]
  const float* A  = (const float*)d_in[4];   // [8,16,2048]
  const float* Bw = (const float*)d_in[5];   // [8,2048,16]
  float* out = (float*)d_out;                // [4,4096,2048] fp32

  ushort_t* xext = (ushort_t*)d_ws;                                   // M_ x KX bf16
  ushort_t* wext = (ushort_t*)((char*)d_ws + (size_t)M_ * KX * 2);    // OUT_ x KX bf16
  ushort_t* aext = (ushort_t*)((char*)d_ws + (size_t)M_ * KX * 2
                                           + (size_t)OUT_ * KX * 2);  // 128 x D_ bf16

  wprep_all_kernel<<<OUT_ + (E_ * R_ * D_) / (256 * 8), 256, 0, stream>>>(Wb, Bw, A, wext, aext);
  tokwave_kernel<<<M_ / 4, 256, 0, stream>>>(x, rW, aext, xext);
  gemm_kernel<<<(M_ / 256) * (OUT_ / 256), 512, 0, stream>>>(xext, wext, bb, out);
}